// Round 3
// baseline (141.583 us; speedup 1.0000x reference)
//
#include <hip/hip_runtime.h>

// Problem constants (fixed by setup_inputs: x = [8, 4096, 512] float32)
#define BB 8
#define TT 4096
#define CC 512
#define C4 (CC / 4)          // 128 float4 per row
#define CHUNK 32             // t-steps per block (held in registers)
#define NCHUNK (TT / CHUNK)  // 128 chunks per batch
#define LOG2_NCHUNK 7
#define NBLK (BB * NCHUNK)   // 1024 blocks

__device__ __forceinline__ void acc4(float4& a, const float4& b) {
    a.x += b.x; a.y += b.y; a.z += b.z; a.w += b.w;
}

// Single-pass causal cumulative mean with decoupled lookback.
// Grid = 1024 blocks x 128 threads; thread owns one float4 column (4 chans).
// Phase 1: load CHUNK rows into registers, publish chunk-sum row + flag.
// Phase 2: wait for predecessor flags (same batch), sum their aggregate rows
//          (L2/IF$-resident, 2 KiB each), then scan registers, scale, store.
__global__ __launch_bounds__(128) void cbow_onepass(
    const float4* __restrict__ in4, float4* __restrict__ agg4,
    unsigned int* __restrict__ flags, float4* __restrict__ out4) {
    const int blk   = blockIdx.x;
    const int b     = blk >> LOG2_NCHUNK;
    const int chunk = blk & (NCHUNK - 1);
    const int c4    = threadIdx.x;

    const size_t base = ((size_t)b * TT + (size_t)chunk * CHUNK) * C4 + c4;

    // ---- Phase 1: load chunk into registers, compute + publish chunk sum ----
    float4 v[CHUNK];
    float4 acc = make_float4(0.f, 0.f, 0.f, 0.f);
#pragma unroll
    for (int t = 0; t < CHUNK; ++t) {
        v[t] = in4[base + (size_t)t * C4];
        acc4(acc, v[t]);
    }
    agg4[(size_t)blk * C4 + c4] = acc;
    __threadfence();     // make the row visible at device scope
    __syncthreads();     // all 128 threads' stores+fences done
    if (threadIdx.x == 0) {
        __hip_atomic_store(&flags[blk], 1u, __ATOMIC_RELEASE,
                           __HIP_MEMORY_SCOPE_AGENT);
    }

    // ---- Phase 2: wait for predecessors (chunks 0..chunk-1 of this b) ----
    const int first = blk - chunk;   // block index of this b's chunk 0
    for (int k = first; k < blk; ++k) {
        while (__hip_atomic_load(&flags[k], __ATOMIC_RELAXED,
                                 __HIP_MEMORY_SCOPE_AGENT) == 0u) {
            __builtin_amdgcn_s_sleep(2);
        }
    }
    if (chunk != 0) {
        __builtin_amdgcn_fence(__ATOMIC_ACQUIRE, "agent");
    }

    // Sum predecessor aggregate rows (independent coalesced loads).
    float4 run = make_float4(0.f, 0.f, 0.f, 0.f);
    const size_t wbase = (size_t)first * C4 + c4;
#pragma unroll 4
    for (int k = 0; k < chunk; ++k) {
        float4 s = agg4[wbase + (size_t)k * C4];
        acc4(run, s);
    }

    // ---- Local scan over register-held rows, scale by 1/(t+1), store ----
#pragma unroll
    for (int t = 0; t < CHUNK; ++t) {
        acc4(run, v[t]);
        const float inv = 1.0f / (float)(chunk * CHUNK + t + 1);
        float4 o;
        o.x = run.x * inv; o.y = run.y * inv;
        o.z = run.z * inv; o.w = run.w * inv;
        out4[base + (size_t)t * C4] = o;
    }
}

extern "C" void kernel_launch(void* const* d_in, const int* in_sizes, int n_in,
                              void* d_out, int out_size, void* d_ws, size_t ws_size,
                              hipStream_t stream) {
    const float4* in4  = (const float4*)d_in[0];
    float4*       out4 = (float4*)d_out;
    // ws layout: [0, 2 MiB)   aggregate rows (NBLK * C4 float4)
    //            [2 MiB, +4K) flags (NBLK u32)
    float4*       agg4  = (float4*)d_ws;
    unsigned int* flags = (unsigned int*)((char*)d_ws + (size_t)NBLK * C4 * sizeof(float4));

    hipMemsetAsync(flags, 0, NBLK * sizeof(unsigned int), stream);

    dim3 grid(NBLK);
    dim3 block(128);
    cbow_onepass<<<grid, block, 0, stream>>>(in4, agg4, flags, out4);
}

// Round 5
// 132.656 us; speedup vs baseline: 1.0673x; 1.0673x over previous
//
#include <hip/hip_runtime.h>

// Problem constants (fixed by setup_inputs: x = [8, 4096, 512] float32)
#define BB 8
#define TT 4096
#define CC 512
#define C4 (CC / 4)          // 128 float4 per row
#define CHUNK 32             // t-steps per block (held in registers)
#define NCHUNK (TT / CHUNK)  // 128 chunks per batch
#define LOG2_NCHUNK 7
#define NBLK (BB * NCHUNK)   // 1024 blocks

typedef float fv4 __attribute__((ext_vector_type(4)));

// Single-pass causal cumulative mean with decoupled lookback.
// Grid = 1024 blocks x 128 threads; thread owns one fv4 column (4 chans).
// Phase 1: load CHUNK rows into registers, publish chunk-sum row + flag.
// Phase 2: LANE-PARALLEL wait on predecessor flags (thread i polls flag
//          first+i), then sum predecessor aggregate rows (independent
//          coalesced L2/IF$ loads), scan registers, scale, store (nt).
__global__ __launch_bounds__(128) void cbow_onepass(
    const fv4* __restrict__ in4, fv4* __restrict__ agg4,
    unsigned int* __restrict__ flags, fv4* __restrict__ out4) {
    const int blk   = blockIdx.x;
    const int b     = blk >> LOG2_NCHUNK;
    const int chunk = blk & (NCHUNK - 1);
    const int c4    = threadIdx.x;

    const size_t base = ((size_t)b * TT + (size_t)chunk * CHUNK) * C4 + c4;

    // ---- Phase 1: load chunk into registers, compute + publish chunk sum ----
    fv4 v[CHUNK];
    fv4 acc = (fv4)0.0f;
#pragma unroll
    for (int t = 0; t < CHUNK; ++t) {
        v[t] = in4[base + (size_t)t * C4];
        acc += v[t];
    }
    agg4[(size_t)blk * C4 + c4] = acc;
    __threadfence();     // make the row visible at device scope
    __syncthreads();     // all 128 threads' stores+fences done
    if (threadIdx.x == 0) {
        __hip_atomic_store(&flags[blk], 1u, __ATOMIC_RELEASE,
                           __HIP_MEMORY_SCOPE_AGENT);
    }

    // ---- Phase 2: lane-parallel wait for predecessors ----
    const int first = blk - chunk;   // block index of this b's chunk 0
    if (threadIdx.x < chunk) {
        while (__hip_atomic_load(&flags[first + threadIdx.x], __ATOMIC_RELAXED,
                                 __HIP_MEMORY_SCOPE_AGENT) == 0u) {
            __builtin_amdgcn_s_sleep(1);
        }
    }
    __syncthreads();     // all predecessor flags observed set
    if (chunk != 0) {
        __builtin_amdgcn_fence(__ATOMIC_ACQUIRE, "agent");
    }

    // Sum predecessor aggregate rows (independent coalesced loads).
    fv4 run = (fv4)0.0f;
    const size_t wbase = (size_t)first * C4 + c4;
#pragma unroll 4
    for (int k = 0; k < chunk; ++k) {
        run += agg4[wbase + (size_t)k * C4];
    }

    // ---- Local scan over register-held rows, scale by 1/(t+1), store ----
#pragma unroll
    for (int t = 0; t < CHUNK; ++t) {
        run += v[t];
        const float inv = 1.0f / (float)(chunk * CHUNK + t + 1);
        fv4 o = run * inv;
        __builtin_nontemporal_store(o, &out4[base + (size_t)t * C4]);
    }
}

extern "C" void kernel_launch(void* const* d_in, const int* in_sizes, int n_in,
                              void* d_out, int out_size, void* d_ws, size_t ws_size,
                              hipStream_t stream) {
    const fv4* in4  = (const fv4*)d_in[0];
    fv4*       out4 = (fv4*)d_out;
    // ws layout: [0, 2 MiB)   aggregate rows (NBLK * C4 fv4)
    //            [2 MiB, +4K) flags (NBLK u32)
    fv4*          agg4  = (fv4*)d_ws;
    unsigned int* flags = (unsigned int*)((char*)d_ws + (size_t)NBLK * C4 * sizeof(fv4));

    (void)hipMemsetAsync(flags, 0, NBLK * sizeof(unsigned int), stream);

    dim3 grid(NBLK);
    dim3 block(128);
    cbow_onepass<<<grid, block, 0, stream>>>(in4, agg4, flags, out4);
}

// Round 6
// 49.312 us; speedup vs baseline: 2.8712x; 2.6901x over previous
//
#include <hip/hip_runtime.h>

// Problem constants (fixed by setup_inputs: x = [8, 4096, 512] float32)
#define BB 8
#define TT 4096
#define CC 512
#define C4 (CC / 4)          // 128 float4 per row
#define CHUNK 32             // t-steps per block (held in registers)
#define NCHUNK (TT / CHUNK)  // 128 chunks per batch
#define LOG2_NCHUNK 7
#define NBLK (BB * NCHUNK)   // 1024 blocks

typedef float fv4 __attribute__((ext_vector_type(4)));

// Single-pass causal cumulative mean with decoupled lookback.
// Coherence is per-access (sc0 sc1 = L2-bypass to the Infinity Cache), NOT
// whole-cache fences: no __threadfence (buffer_wbl2) / acquire (buffer_inv).
// Safety of plain lookback loads: L2 is invalidated at dispatch start
// (implicit HSA acquire), and each agg line is first touched only after its
// producer's flag is set, so the clean miss fetches the IF$-current value.
__global__ __launch_bounds__(128) void cbow_onepass(
    const fv4* __restrict__ in4, fv4* __restrict__ agg4,
    unsigned int* __restrict__ flags, fv4* __restrict__ out4) {
    const int blk   = blockIdx.x;
    const int b     = blk >> LOG2_NCHUNK;
    const int chunk = blk & (NCHUNK - 1);
    const int c4    = threadIdx.x;

    const size_t base = ((size_t)b * TT + (size_t)chunk * CHUNK) * C4 + c4;

    // ---- Phase 1: load chunk into registers, compute chunk sum ----
    fv4 v[CHUNK];
    fv4 acc = (fv4)0.0f;
#pragma unroll
    for (int t = 0; t < CHUNK; ++t) {
        v[t] = in4[base + (size_t)t * C4];
        acc += v[t];
    }

    // Publish chunk-sum row straight to the coherence point (IF$), then wait
    // for the write-ack before raising the flag. No cache-wide fence.
    {
        fv4* p = &agg4[(size_t)blk * C4 + c4];
        asm volatile("global_store_dwordx4 %0, %1, off sc0 sc1"
                     :: "v"(p), "v"(acc) : "memory");
        asm volatile("s_waitcnt vmcnt(0)" ::: "memory");
    }
    __syncthreads();     // all 128 threads' coherent stores acked
    if (threadIdx.x == 0) {
        __hip_atomic_store(&flags[blk], 1u, __ATOMIC_RELAXED,
                           __HIP_MEMORY_SCOPE_AGENT);
    }

    // ---- Phase 2: lane-parallel wait for predecessors (no acquire fence) ----
    const int first = blk - chunk;   // block index of this b's chunk 0
    if (threadIdx.x < chunk) {
        while (__hip_atomic_load(&flags[first + threadIdx.x], __ATOMIC_RELAXED,
                                 __HIP_MEMORY_SCOPE_AGENT) == 0u) {
            __builtin_amdgcn_s_sleep(2);
        }
    }
    __syncthreads();     // all predecessor flags observed set

    // Sum predecessor aggregate rows (plain vector loads, full ILP).
    fv4 run = (fv4)0.0f;
    const size_t wbase = (size_t)first * C4 + c4;
#pragma unroll 4
    for (int k = 0; k < chunk; ++k) {
        run += agg4[wbase + (size_t)k * C4];
    }

    // ---- Local scan over register-held rows, scale by 1/(t+1), store ----
#pragma unroll
    for (int t = 0; t < CHUNK; ++t) {
        run += v[t];
        const float inv = 1.0f / (float)(chunk * CHUNK + t + 1);
        fv4 o = run * inv;
        __builtin_nontemporal_store(o, &out4[base + (size_t)t * C4]);
    }
}

extern "C" void kernel_launch(void* const* d_in, const int* in_sizes, int n_in,
                              void* d_out, int out_size, void* d_ws, size_t ws_size,
                              hipStream_t stream) {
    const fv4* in4  = (const fv4*)d_in[0];
    fv4*       out4 = (fv4*)d_out;
    // ws layout: [0, 2 MiB)   aggregate rows (NBLK * C4 fv4)
    //            [2 MiB, +4K) flags (NBLK u32)
    fv4*          agg4  = (fv4*)d_ws;
    unsigned int* flags = (unsigned int*)((char*)d_ws + (size_t)NBLK * C4 * sizeof(fv4));

    (void)hipMemsetAsync(flags, 0, NBLK * sizeof(unsigned int), stream);

    dim3 grid(NBLK);
    dim3 block(128);
    cbow_onepass<<<grid, block, 0, stream>>>(in4, agg4, flags, out4);
}

// Round 7
// 34.122 us; speedup vs baseline: 4.1493x; 1.4452x over previous
//
#include <hip/hip_runtime.h>

// Problem constants (fixed by setup_inputs: x = [8, 4096, 512] float32)
#define BB 8
#define TT 4096
#define CC 512
#define C4 (CC / 4)          // 128 float4 columns per row
#define CHUNK 128            // t-steps per block (4 quarters x 32 rows in regs)
#define NCHUNK (TT / CHUNK)  // 32 chunks per batch
#define LOG2_NCHUNK 5
#define NBLK (BB * NCHUNK)   // 256 blocks
#define QROWS 32             // rows per quarter (held in registers)

typedef float fv4 __attribute__((ext_vector_type(4)));

// Single-pass causal cumulative mean with flat decoupled lookback.
// 256 blocks x 512 threads. Thread (q, c4) owns rows [chunk*128 + q*32 ..
// +31] of fv4-column c4. Phase 1: load 32 rows to regs, quarter column-sums
// combine via LDS; quarter 3 publishes the block-sum row straight to the
// IF$ (sc0 sc1, per-access coherence -- no cache-wide fences). Phase 2:
// wave-0 lanes poll predecessor flags (<=31), then every thread sums
// predecessor aggregate rows + its exclusive quarter offset, scans its 32
// register rows, scales by 1/(t+1), nt-stores.
__global__ __launch_bounds__(512) void cbow_onepass(
    const fv4* __restrict__ in4, fv4* __restrict__ agg4,
    unsigned int* __restrict__ flags, fv4* __restrict__ out4) {
    const int blk   = blockIdx.x;
    const int b     = blk >> LOG2_NCHUNK;
    const int chunk = blk & (NCHUNK - 1);
    const int tid   = threadIdx.x;
    const int q     = tid >> 7;      // quarter 0..3
    const int c4    = tid & (C4 - 1);

    __shared__ fv4 lds[4][C4];

    const size_t base =
        ((size_t)b * TT + (size_t)chunk * CHUNK + (size_t)q * QROWS) * C4 + c4;

    // ---- Phase 1: load 32 rows into registers, quarter column sum ----
    fv4 v[QROWS];
    fv4 qsum = (fv4)0.0f;
#pragma unroll
    for (int t = 0; t < QROWS; ++t) {
        v[t] = in4[base + (size_t)t * C4];
        qsum += v[t];
    }
    lds[q][c4] = qsum;
    __syncthreads();

    // Exclusive within-block quarter offset; quarter 3 derives block total.
    fv4 excl = (fv4)0.0f;
#pragma unroll
    for (int p = 0; p < 3; ++p) {
        if (p < q) excl += lds[p][c4];
    }

    if (q == 3) {
        fv4 total = excl + qsum;
        fv4* p = &agg4[(size_t)blk * C4 + c4];
        asm volatile("global_store_dwordx4 %0, %1, off sc0 sc1"
                     :: "v"(p), "v"(total) : "memory");
        asm volatile("s_waitcnt vmcnt(0)" ::: "memory");
    }
    __syncthreads();     // publishing stores acked before flag
    if (tid == 0) {
        __hip_atomic_store(&flags[blk], 1u, __ATOMIC_RELAXED,
                           __HIP_MEMORY_SCOPE_AGENT);
    }

    // ---- Phase 2: lane-parallel wait for predecessors (wave 0 only) ----
    const int first = blk - chunk;   // block index of this batch's chunk 0
    if (tid < chunk) {               // chunk <= 31 -> single wave polls
        while (__hip_atomic_load(&flags[first + tid], __ATOMIC_RELAXED,
                                 __HIP_MEMORY_SCOPE_AGENT) == 0u) {
            __builtin_amdgcn_s_sleep(2);
        }
    }
    __syncthreads();     // all predecessor flags observed set

    // Sum predecessor aggregate rows (plain vector loads, full ILP).
    fv4 run = excl;
    const size_t wbase = (size_t)first * C4 + c4;
#pragma unroll 4
    for (int k = 0; k < chunk; ++k) {
        run += agg4[wbase + (size_t)k * C4];
    }

    // ---- Local scan over register-held rows, scale by 1/(t+1), store ----
    const int t0 = chunk * CHUNK + q * QROWS;  // global t of first own row
#pragma unroll
    for (int t = 0; t < QROWS; ++t) {
        run += v[t];
        const float inv = 1.0f / (float)(t0 + t + 1);
        fv4 o = run * inv;
        __builtin_nontemporal_store(o, &out4[base + (size_t)t * C4]);
    }
}

extern "C" void kernel_launch(void* const* d_in, const int* in_sizes, int n_in,
                              void* d_out, int out_size, void* d_ws, size_t ws_size,
                              hipStream_t stream) {
    const fv4* in4  = (const fv4*)d_in[0];
    fv4*       out4 = (fv4*)d_out;
    // ws layout: [0, 512 KiB)   aggregate rows (NBLK * C4 fv4)
    //            [512 KiB, +1K) flags (NBLK u32)
    fv4*          agg4  = (fv4*)d_ws;
    unsigned int* flags = (unsigned int*)((char*)d_ws + (size_t)NBLK * C4 * sizeof(fv4));

    (void)hipMemsetAsync(flags, 0, NBLK * sizeof(unsigned int), stream);

    dim3 grid(NBLK);
    dim3 block(512);
    cbow_onepass<<<grid, block, 0, stream>>>(in4, agg4, flags, out4);
}